// Round 6
// baseline (461.431 us; speedup 1.0000x reference)
//
#include <hip/hip_runtime.h>
#include <math.h>

// Problem constants (from reference)
constexpr int T_ = 131072;
constexpr int E_ = 512;
constexpr int H_ = 512;
constexpr int K_ = 1024;
constexpr int L_ = 128;
constexpr unsigned NB_TAIL = 512;   // tail grid: 512 blocks x 256 thr (8x co-residency margin)

typedef __attribute__((ext_vector_type(4))) float f32x4;

// Workspace layout (element offsets; floats unless noted)
constexpr size_t OFF_V     = 0;                    // 512 f
constexpr size_t OFF_ALPHA = 512;                  // 131072 f (reused as attn partials)
constexpr size_t OFF_HIST1 = OFF_ALPHA + T_;       // 65536 u32
constexpr size_t OFF_HIST2 = OFF_HIST1 + 65536;    // 65536 u32
constexpr size_t OFF_CNT   = OFF_HIST2 + 65536;    // 2 u32
constexpr size_t OFF_CTR   = OFF_CNT + 2;          // 8 u32 grid-barrier counters
constexpr size_t OFF_INFO  = OFF_CTR + 8;          // 8 u32
constexpr size_t OFF_VALS  = OFF_INFO + 8;         // 1024 f
constexpr size_t OFF_IDX   = OFF_VALS + K_;        // 1024 i32
constexpr size_t OFF_GI    = OFF_IDX + K_;         // 1536 f
constexpr size_t OFF_GH    = OFF_GI + 3 * H_;      // 1536 f

// Zeroed-per-call contiguous region: hist1 + hist2 + cnt + ctr
constexpr int ZERO_N = 65536 + 65536 + 2 + 8;

// Output layout: score(1) | h_new(512) | vs_new((T+1)*512) | hs_new((T+1)*512)
constexpr size_t OUT_VS = 513;
constexpr size_t OUT_HS = 513 + (size_t)(T_ + 1) * E_;

__device__ __forceinline__ unsigned fkey(float f) {
    unsigned u = __float_as_uint(f);
    return (u & 0x80000000u) ? ~u : (u | 0x80000000u);  // ascending key == ascending float
}

// Software grid barrier: counters monotonically increase within a call and are
// re-zeroed by k_init each call (graph-replay safe). 512 blocks all co-resident
// (<=64 VGPR, 6KB LDS -> >=8 blocks/CU capacity vs 2 needed).
__device__ __forceinline__ void gbar(unsigned* c) {
    __syncthreads();
    if (threadIdx.x == 0) {
        __hip_atomic_fetch_add(c, 1u, __ATOMIC_ACQ_REL, __HIP_MEMORY_SCOPE_AGENT);
        while (__hip_atomic_load(c, __ATOMIC_ACQUIRE, __HIP_MEMORY_SCOPE_AGENT) < NB_TAIL)
            __builtin_amdgcn_s_sleep(4);
    }
    __syncthreads();
}

// Last block: v = mean(emb[topic]) (two 512-thread halves, deterministic order).
// Other blocks: zero hist1+hist2+cnt+ctr (ZERO_N u32, contiguous).
__global__ __launch_bounds__(1024) void k_init(const int* __restrict__ topic,
                                               const float* __restrict__ emb,
                                               float* __restrict__ ws_v,
                                               unsigned* __restrict__ zero_base,
                                               float* __restrict__ out) {
    if (blockIdx.x == gridDim.x - 1) {
        __shared__ float part[512];
        int t = threadIdx.x;
        int e = t & 511, g = t >> 9;       // g in {0,1}
        float s = 0.f;
        #pragma unroll 8
        for (int l = g * 64; l < g * 64 + 64; ++l) {
            int tp = topic[l];
            s += emb[(size_t)tp * E_ + e];
        }
        if (g == 1) part[e] = s;
        __syncthreads();
        if (g == 0) {
            float v = (s + part[e]) * (1.0f / L_);
            ws_v[e] = v;
            out[OUT_VS + (size_t)T_ * E_ + e] = v;  // vs_new last row
        }
    } else {
        int i = blockIdx.x * blockDim.x + threadIdx.x;
        if (i < ZERO_N) zero_base[i] = 0u;
    }
}

// Mega kernel: fused {vs copy + alpha dot + hist1} and {hs copy}.
// NT loads (single-use stream), PLAIN stores (let L2 merge the 4B-misaligned
// row seams: row r's 4B tail partial-line and row r+1's 60B head partial-line
// are the SAME 64B line written by different waves -> L2 write-combining turns
// them into full-line HBM writes; nt no-allocate stores forfeited that).
// ONE atomic per row to the 65536-bin hist (~2/bin; NEVER a low-cardinality
// counter here: R4's 512-bin chunk atomic serialized ~40K deep, 4x slowdown).
__global__ __launch_bounds__(256) void k_mega(const float* __restrict__ vs,
                                              const float* __restrict__ hs,
                                              const float* __restrict__ ws_v,
                                              float* __restrict__ alpha,
                                              unsigned* __restrict__ hist1,
                                              float* __restrict__ out) {
    int wave = threadIdx.x >> 6, lane = threadIdx.x & 63;
    int b = blockIdx.x;
    bool is_vs = b < (T_ / 4);
    int row = (is_vs ? b : b - T_ / 4) * 4 + wave;
    const f32x4* src4 = (const f32x4*)((is_vs ? vs : hs) + (size_t)row * E_);
    f32x4 a0 = __builtin_nontemporal_load(&src4[lane]);
    f32x4 a1 = __builtin_nontemporal_load(&src4[lane + 64]);
    if (is_vs) {
        const f32x4* v4 = (const f32x4*)ws_v;
        f32x4 b0 = v4[lane];
        f32x4 b1 = v4[lane + 64];
        float dot = 0.f;
        dot = fmaf(a0.x, b0.x, dot); dot = fmaf(a0.y, b0.y, dot);
        dot = fmaf(a0.z, b0.z, dot); dot = fmaf(a0.w, b0.w, dot);
        dot = fmaf(a1.x, b1.x, dot); dot = fmaf(a1.y, b1.y, dot);
        dot = fmaf(a1.z, b1.z, dot); dot = fmaf(a1.w, b1.w, dot);
        #pragma unroll
        for (int m = 32; m; m >>= 1) dot += __shfl_xor(dot, m, 64);
        if (lane == 0) {
            alpha[row] = dot;
            atomicAdd(&hist1[fkey(dot) >> 16], 1u);
        }
    }
    // Shuffle-rotate realignment
    int nl = (lane + 1) & 63;
    float n0x = __shfl(a0.x, nl, 64), n0y = __shfl(a0.y, nl, 64), n0z = __shfl(a0.z, nl, 64);
    float n1x = __shfl(a1.x, nl, 64), n1y = __shfl(a1.y, nl, 64), n1z = __shfl(a1.z, nl, 64);
    float* dst = out + (is_vs ? OUT_VS : OUT_HS) + (size_t)row * E_;
    f32x4* d4 = (f32x4*)(dst + 3);            // 16B-aligned
    bool last = (lane == 63);
    f32x4 lo;
    lo.x = a0.w;
    lo.y = last ? n1x : n0x;   // lane 63: e[256..258] = a1.xyz of lane 0
    lo.z = last ? n1y : n0y;
    lo.w = last ? n1z : n0z;
    d4[lane] = lo;
    if (!last) {
        f32x4 hi;
        hi.x = a1.w; hi.y = n1x; hi.z = n1y; hi.w = n1z;
        d4[lane + 64] = hi;
    }
    if (lane == 0) { dst[0] = a0.x; dst[1] = a0.y; dst[2] = a0.z; }
    if (last) dst[511] = a1.w;
}

// Fully-parallel descending select over a 65536-bin histogram (verified R5).
// ps must have 258 u32 of shared. Run by one block's 256 threads.
__device__ void scan_body(const unsigned* __restrict__ hist,
                          unsigned* __restrict__ info, int pass, unsigned* ps) {
    int t = threadIdx.x;
    unsigned Kwant = (pass == 0) ? (unsigned)K_ : ((unsigned)K_ - info[1]);
    unsigned base = 65536u - (unsigned)(t + 1) * 256u;
    unsigned s = 0;
    for (int j = 0; j < 256; ++j) s += hist[base + j];
    ps[t] = s;
    __syncthreads();
    #pragma unroll
    for (int off = 1; off < 256; off <<= 1) {
        unsigned v = (t >= off) ? ps[t - off] : 0u;
        __syncthreads();
        ps[t] += v;
        __syncthreads();
    }
    unsigned incl = ps[t], excl = incl - s;
    if (excl < Kwant && incl >= Kwant) { ps[256] = (unsigned)t; ps[257] = excl; }
    __syncthreads();
    unsigned c = ps[256], above = ps[257];
    unsigned Kw2 = Kwant - above;
    unsigned bin = 65535u - c * 256u - (unsigned)t;
    unsigned bv = hist[bin];
    __syncthreads();
    ps[t] = bv;
    __syncthreads();
    #pragma unroll
    for (int off = 1; off < 256; off <<= 1) {
        unsigned v = (t >= off) ? ps[t - off] : 0u;
        __syncthreads();
        ps[t] += v;
        __syncthreads();
    }
    unsigned inc2 = ps[t], ex2 = inc2 - bv;
    if (ex2 < Kw2 && inc2 >= Kw2) {
        unsigned ca = above + ex2;
        if (pass == 0) { info[0] = bin; info[1] = ca; }
        else {
            info[2] = (info[0] << 16) | bin;
            info[3] = info[1] + ca;
            info[4] = (unsigned)K_ - info[3];
        }
    }
}

// Fused tail: scan0 | hist2 | scan1 | select | attn||gru | final, separated by
// software grid barriers. 512 blocks x 256 threads, one element per thread for
// the T=131072-wide phases.
__global__ __launch_bounds__(256) void k_tail(
    const float* __restrict__ alpha_r, float* __restrict__ part,
    unsigned* __restrict__ hist1, unsigned* __restrict__ hist2,
    unsigned* __restrict__ cnt, unsigned* __restrict__ info,
    unsigned* __restrict__ ctr,
    float* __restrict__ vals, int* __restrict__ idx,
    const float* __restrict__ hs,
    const float* __restrict__ wih, const float* __restrict__ whh,
    const float* __restrict__ bih, const float* __restrict__ bhh,
    const float* __restrict__ ws_v, const float* __restrict__ score_s,
    const float* __restrict__ h_in,
    float* __restrict__ gi, float* __restrict__ gh,
    const float* __restrict__ w_score, const float* __restrict__ b_score,
    float* __restrict__ out)
{
    __shared__ float shf[1544];
    unsigned* shu = (unsigned*)shf;
    int t = threadIdx.x, b = blockIdx.x;
    int i = b * 256 + t;

    // phase 0: scan pass 0 (block 0)
    if (b == 0) scan_body(hist1, info, 0, shu);
    gbar(&ctr[0]);

    // phase 1: hist2 fill (alpha/key kept in registers for phase 3)
    float av = alpha_r[i];
    unsigned key = fkey(av);
    if ((key >> 16) == info[0]) atomicAdd(&hist2[key & 0xFFFFu], 1u);
    gbar(&ctr[1]);

    // phase 2: scan pass 1 (block 0)
    if (b == 0) scan_body(hist2, info, 1, shu);
    gbar(&ctr[2]);

    // phase 3: select
    {
        unsigned thr = info[2];
        if (key > thr) {
            unsigned p = atomicAdd(&cnt[0], 1u);
            vals[p] = av; idx[p] = i;
        } else if (key == thr) {
            unsigned tt = atomicAdd(&cnt[1], 1u);
            if (tt < info[4]) {
                unsigned p = info[3] + tt;
                vals[p] = av; idx[p] = i;
            }
        }
    }
    gbar(&ctr[3]);

    // phase 4: attn (blocks 0..127: 8 rows each, 2 cols/thread) | gru gates
    if (b < 128) {
        float v0 = vals[t], v1 = vals[t + 256], v2 = vals[t + 512], v3 = vals[t + 768];
        shf[t] = fmaxf(fmaxf(v0, v1), fmaxf(v2, v3));
        __syncthreads();
        for (int s = 128; s > 0; s >>= 1) { if (t < s) shf[t] = fmaxf(shf[t], shf[t + s]); __syncthreads(); }
        float m = shf[0];
        __syncthreads();
        shf[t] = expf(v0 - m) + expf(v1 - m) + expf(v2 - m) + expf(v3 - m);
        __syncthreads();
        for (int s = 128; s > 0; s >>= 1) { if (t < s) shf[t] += shf[t + s]; __syncthreads(); }
        float S = shf[0];
        float acc0 = 0.f, acc1 = 0.f;
        #pragma unroll
        for (int k = b * 8; k < b * 8 + 8; ++k) {
            float w = expf(vals[k] - m) / S;
            const float* hr = hs + (size_t)idx[k] * E_;
            acc0 = fmaf(w, hr[t], acc0);
            acc1 = fmaf(w, hr[t + 256], acc1);
        }
        part[(size_t)b * E_ + t] = acc0;
        part[(size_t)b * E_ + t + 256] = acc1;
    } else {
        int bb = b - 128;                      // 0..383, one gate-row per wave
        float ss = score_s[0];
        float pos = ss >= 0.5f ? 1.f : 0.f;
        for (int c = t; c < 1025; c += 256) {
            float xv;
            if (c < 512)       xv = ws_v[c] * pos;
            else if (c < 1024) xv = ws_v[c - 512] * (1.f - pos);
            else               xv = ss;
            shf[c] = xv;
        }
        for (int c = t; c < 512; c += 256) shf[1025 + c] = h_in[c];
        __syncthreads();
        int wave = t >> 6, lane = t & 63;
        int row = bb * 4 + wave;
        const float* wr = wih + (size_t)row * 1025;
        float s1 = 0.f;
        for (int c = lane; c < 1025; c += 64) s1 = fmaf(wr[c], shf[c], s1);
        const float* hr2 = whh + (size_t)row * 512;
        float s2 = 0.f;
        #pragma unroll
        for (int c = lane; c < 512; c += 64) s2 = fmaf(hr2[c], shf[1025 + c], s2);
        #pragma unroll
        for (int m2 = 32; m2; m2 >>= 1) {
            s1 += __shfl_xor(s1, m2, 64);
            s2 += __shfl_xor(s2, m2, 64);
        }
        if (lane == 0) { gi[row] = s1 + bih[row]; gh[row] = s2 + bhh[row]; }
    }
    gbar(&ctr[4]);

    // phase 5: final = GRU-finalize + score (block 0, 2 j's per thread)
    if (b == 0) {
        float dsum = 0.f;
        #pragma unroll
        for (int half = 0; half < 2; ++half) {
            int j = t + half * 256;
            float r = 1.f / (1.f + expf(-(gi[j] + gh[j])));
            float z = 1.f / (1.f + expf(-(gi[H_ + j] + gh[H_ + j])));
            float n = tanhf(gi[2 * H_ + j] + r * gh[2 * H_ + j]);
            float hp = h_in[j];
            float hn = (1.f - z) * n + z * hp;
            out[1 + j] = hn;                          // h_new
            out[OUT_HS + (size_t)T_ * E_ + j] = hn;   // hs_new last row
            float attn = 0.f;
            for (int jj = 0; jj < 128; ++jj) attn += part[(size_t)jj * E_ + j];
            dsum += ws_v[j] * w_score[j] + attn * w_score[512 + j] + hp * w_score[1024 + j];
        }
        if (t == 0) dsum += 1024.0f * w_score[1536] + b_score[0];
        shf[t] = dsum;
        __syncthreads();
        for (int s = 128; s > 0; s >>= 1) { if (t < s) shf[t] += shf[t + s]; __syncthreads(); }
        if (t == 0) out[0] = shf[0];
    }
}

extern "C" void kernel_launch(void* const* d_in, const int* in_sizes, int n_in,
                              void* d_out, int out_size, void* d_ws, size_t ws_size,
                              hipStream_t stream) {
    const int*   topic   = (const int*)d_in[0];
    const float* score_s = (const float*)d_in[1];
    const float* emb     = (const float*)d_in[2];
    const float* h_in    = (const float*)d_in[3];
    const float* vs      = (const float*)d_in[4];
    const float* hs      = (const float*)d_in[5];
    const float* w_ih    = (const float*)d_in[6];
    const float* w_hh    = (const float*)d_in[7];
    const float* b_ih    = (const float*)d_in[8];
    const float* b_hh    = (const float*)d_in[9];
    const float* w_score = (const float*)d_in[10];
    const float* b_score = (const float*)d_in[11];
    float* out = (float*)d_out;

    float*    wsf   = (float*)d_ws;
    float*    v_ws  = wsf + OFF_V;
    float*    alpha = wsf + OFF_ALPHA;
    unsigned* hist1 = (unsigned*)(wsf + OFF_HIST1);
    unsigned* hist2 = (unsigned*)(wsf + OFF_HIST2);
    unsigned* cnt   = (unsigned*)(wsf + OFF_CNT);
    unsigned* ctr   = (unsigned*)(wsf + OFF_CTR);
    unsigned* info  = (unsigned*)(wsf + OFF_INFO);
    float*    vals  = wsf + OFF_VALS;
    int*      idx   = (int*)(wsf + OFF_IDX);
    float*    part  = wsf + OFF_ALPHA;  // alpha dead after select phase; reuse
    float*    gi    = wsf + OFF_GI;
    float*    gh    = wsf + OFF_GH;

    // 1) v + zero-init (blocks 0..128 zero ZERO_N u32; block 129 computes v)
    hipLaunchKernelGGL(k_init, dim3(130), dim3(1024), 0, stream,
                       topic, emb, v_ws, hist1, out);
    // 2) fused copies + alpha + hist1
    hipLaunchKernelGGL(k_mega, dim3(2 * (T_ / 4)), dim3(256), 0, stream,
                       vs, hs, v_ws, alpha, hist1, out);
    // 3) fused tail: scan0|hist2|scan1|select|attn+gru|final
    hipLaunchKernelGGL(k_tail, dim3(NB_TAIL), dim3(256), 0, stream,
                       alpha, part, hist1, hist2, cnt, info, ctr, vals, idx,
                       hs, w_ih, w_hh, b_ih, b_hh, v_ws, score_s, h_in,
                       gi, gh, w_score, b_score, out);
}

// Round 7
// 250.897 us; speedup vs baseline: 1.8391x; 1.8391x over previous
//
#include <hip/hip_runtime.h>
#include <math.h>

// Problem constants (from reference)
constexpr int T_ = 131072;
constexpr int E_ = 512;
constexpr int H_ = 512;
constexpr int K_ = 1024;
constexpr int L_ = 128;

typedef __attribute__((ext_vector_type(4))) float f32x4;

// Workspace layout (element offsets; floats unless noted)
constexpr size_t OFF_V     = 0;                    // 512 f
constexpr size_t OFF_ALPHA = 512;                  // 131072 f (reused as attn partials)
constexpr size_t OFF_HIST1 = OFF_ALPHA + T_;       // 65536 u32
constexpr size_t OFF_HIST2 = OFF_HIST1 + 65536;    // 65536 u32
constexpr size_t OFF_CNT   = OFF_HIST2 + 65536;    // 2 u32
constexpr size_t OFF_INFO  = OFF_CNT + 2;          // 8 u32
constexpr size_t OFF_VALS  = OFF_INFO + 8;         // 1024 f
constexpr size_t OFF_IDX   = OFF_VALS + K_;        // 1024 i32
constexpr size_t OFF_GI    = OFF_IDX + K_;         // 1536 f
constexpr size_t OFF_GH    = OFF_GI + 3 * H_;      // 1536 f

// Zeroed-per-call contiguous region: hist1 + hist2 + cnt
constexpr int ZERO_N = 65536 + 65536 + 2;

// Output layout: score(1) | h_new(512) | vs_new((T+1)*512) | hs_new((T+1)*512)
constexpr size_t OUT_VS = 513;
constexpr size_t OUT_HS = 513 + (size_t)(T_ + 1) * E_;

// JOURNAL (measured):
//  R4: low-cardinality chunk atomic in mega -> 40K-deep serialization, 860us. NEVER.
//  R5: separate-kernel tail + parallel LDS scans = 244.9us (known good baseline).
//  R6: software spin grid-barrier tail fusion (5 barriers, 512 blocks, cross-XCD
//      polling) + plain stores = 461us. Kernel-boundary sync (~2-4us) is CHEAPER
//      than device-scope spin barriers (~30-40us each) on 8-XCD MI355X. NEVER again.
//  This round: R5 exact + k_mega 2 rows/wave (deeper load pipeline), sole change.

__device__ __forceinline__ unsigned fkey(float f) {
    unsigned u = __float_as_uint(f);
    return (u & 0x80000000u) ? ~u : (u | 0x80000000u);  // ascending key == ascending float
}

// Last block: v = mean(emb[topic]) (two 512-thread halves, deterministic order).
// Other blocks: zero hist1+hist2+cnt (ZERO_N u32, contiguous).
__global__ __launch_bounds__(1024) void k_init(const int* __restrict__ topic,
                                               const float* __restrict__ emb,
                                               float* __restrict__ ws_v,
                                               unsigned* __restrict__ zero_base,
                                               float* __restrict__ out) {
    if (blockIdx.x == gridDim.x - 1) {
        __shared__ float part[512];
        int t = threadIdx.x;
        int e = t & 511, g = t >> 9;       // g in {0,1}
        float s = 0.f;
        #pragma unroll 8
        for (int l = g * 64; l < g * 64 + 64; ++l) {
            int tp = topic[l];
            s += emb[(size_t)tp * E_ + e];
        }
        if (g == 1) part[e] = s;
        __syncthreads();
        if (g == 0) {
            float v = (s + part[e]) * (1.0f / L_);
            ws_v[e] = v;
            out[OUT_VS + (size_t)T_ * E_ + e] = v;  // vs_new last row
        }
    } else {
        int i = blockIdx.x * blockDim.x + threadIdx.x;
        if (i < ZERO_N) zero_base[i] = 0u;
    }
}

// Store one 512-float row whose destination starts 4B-misaligned (element
// 513+512*row). Realign to 16B via shuffle-rotate; NT stores (R5-verified).
__device__ __forceinline__ void store_row(f32x4 a0, f32x4 a1, float* dst, int lane) {
    int nl = (lane + 1) & 63;
    float n0x = __shfl(a0.x, nl, 64), n0y = __shfl(a0.y, nl, 64), n0z = __shfl(a0.z, nl, 64);
    float n1x = __shfl(a1.x, nl, 64), n1y = __shfl(a1.y, nl, 64), n1z = __shfl(a1.z, nl, 64);
    f32x4* d4 = (f32x4*)(dst + 3);            // 16B-aligned
    bool last = (lane == 63);
    f32x4 lo;
    lo.x = a0.w;
    lo.y = last ? n1x : n0x;   // lane 63: e[256..258] = a1.xyz of lane 0
    lo.z = last ? n1y : n0y;
    lo.w = last ? n1z : n0z;
    __builtin_nontemporal_store(lo, &d4[lane]);
    if (!last) {
        f32x4 hi;
        hi.x = a1.w; hi.y = n1x; hi.z = n1y; hi.w = n1z;
        __builtin_nontemporal_store(hi, &d4[lane + 64]);
    }
    if (lane == 0) { dst[0] = a0.x; dst[1] = a0.y; dst[2] = a0.z; }
    if (last) dst[511] = a1.w;
}

// Mega kernel: fused {vs copy + alpha dot + hist1} and {hs copy}.
// 2 rows per wave: all 4 row-loads issued before any dependent use (deeper
// memory pipeline). NT float4 loads+stores. ONE atomic per row to the
// 65536-bin hist (~2/bin; NEVER a low-cardinality counter here — see R4).
__global__ __launch_bounds__(256) void k_mega(const float* __restrict__ vs,
                                              const float* __restrict__ hs,
                                              const float* __restrict__ ws_v,
                                              float* __restrict__ alpha,
                                              unsigned* __restrict__ hist1,
                                              float* __restrict__ out) {
    int wave = threadIdx.x >> 6, lane = threadIdx.x & 63;
    int b = blockIdx.x;
    bool is_vs = b < (T_ / 8);
    int row0 = (is_vs ? b : b - T_ / 8) * 8 + wave * 2;   // rows row0, row0+1
    const float* src_base = is_vs ? vs : hs;
    const f32x4* s0 = (const f32x4*)(src_base + (size_t)row0 * E_);
    const f32x4* s1 = (const f32x4*)(src_base + (size_t)(row0 + 1) * E_);
    f32x4 a0 = __builtin_nontemporal_load(&s0[lane]);
    f32x4 a1 = __builtin_nontemporal_load(&s0[lane + 64]);
    f32x4 c0 = __builtin_nontemporal_load(&s1[lane]);
    f32x4 c1 = __builtin_nontemporal_load(&s1[lane + 64]);
    if (is_vs) {
        const f32x4* v4 = (const f32x4*)ws_v;
        f32x4 b0 = v4[lane];
        f32x4 b1 = v4[lane + 64];
        float dA = 0.f, dB = 0.f;
        dA = fmaf(a0.x, b0.x, dA); dA = fmaf(a0.y, b0.y, dA);
        dA = fmaf(a0.z, b0.z, dA); dA = fmaf(a0.w, b0.w, dA);
        dA = fmaf(a1.x, b1.x, dA); dA = fmaf(a1.y, b1.y, dA);
        dA = fmaf(a1.z, b1.z, dA); dA = fmaf(a1.w, b1.w, dA);
        dB = fmaf(c0.x, b0.x, dB); dB = fmaf(c0.y, b0.y, dB);
        dB = fmaf(c0.z, b0.z, dB); dB = fmaf(c0.w, b0.w, dB);
        dB = fmaf(c1.x, b1.x, dB); dB = fmaf(c1.y, b1.y, dB);
        dB = fmaf(c1.z, b1.z, dB); dB = fmaf(c1.w, b1.w, dB);
        #pragma unroll
        for (int m = 32; m; m >>= 1) {
            dA += __shfl_xor(dA, m, 64);
            dB += __shfl_xor(dB, m, 64);
        }
        if (lane == 0) {
            alpha[row0] = dA;
            alpha[row0 + 1] = dB;
            atomicAdd(&hist1[fkey(dA) >> 16], 1u);
            atomicAdd(&hist1[fkey(dB) >> 16], 1u);
        }
    }
    float* dst_base = out + (is_vs ? OUT_VS : OUT_HS);
    store_row(a0, a1, dst_base + (size_t)row0 * E_, lane);
    store_row(c0, c1, dst_base + (size_t)(row0 + 1) * E_, lane);
}

// Fully-parallel descending select over a 65536-bin histogram (verified R5).
__global__ __launch_bounds__(256) void k_scan(const unsigned* __restrict__ hist,
                                              unsigned* __restrict__ info, int pass) {
    __shared__ unsigned ps[256];
    __shared__ unsigned s_chunk, s_above;
    int t = threadIdx.x;
    unsigned Kwant = (pass == 0) ? (unsigned)K_ : ((unsigned)K_ - info[1]);
    // phase 1: chunk t covers bins [65536-256(t+1), 65536-256t)
    unsigned base = 65536u - (unsigned)(t + 1) * 256u;
    unsigned s = 0;
    for (int j = 0; j < 256; ++j) s += hist[base + j];
    ps[t] = s;
    __syncthreads();
    // phase 2: inclusive scan (descending-chunk prefix)
    #pragma unroll
    for (int off = 1; off < 256; off <<= 1) {
        unsigned v = (t >= off) ? ps[t - off] : 0u;
        __syncthreads();
        ps[t] += v;
        __syncthreads();
    }
    unsigned incl = ps[t], excl = incl - s;
    if (excl < Kwant && incl >= Kwant) { s_chunk = (unsigned)t; s_above = excl; }
    __syncthreads();
    unsigned c = s_chunk;
    unsigned Kw2 = Kwant - s_above;
    // phase 3: scan winner chunk's bins, descending: bin = 65535-256c-t
    unsigned bin = 65535u - c * 256u - (unsigned)t;
    unsigned b = hist[bin];
    __syncthreads();
    ps[t] = b;
    __syncthreads();
    #pragma unroll
    for (int off = 1; off < 256; off <<= 1) {
        unsigned v = (t >= off) ? ps[t - off] : 0u;
        __syncthreads();
        ps[t] += v;
        __syncthreads();
    }
    unsigned inc2 = ps[t], ex2 = inc2 - b;
    if (ex2 < Kw2 && inc2 >= Kw2) {
        unsigned cnt_above = s_above + ex2;
        if (pass == 0) { info[0] = bin; info[1] = cnt_above; }
        else {
            info[2] = (info[0] << 16) | bin;
            info[3] = info[1] + cnt_above;
            info[4] = (unsigned)K_ - info[3];
        }
    }
}

__global__ __launch_bounds__(256) void k_hist2(const float* __restrict__ alpha,
                                               const unsigned* __restrict__ info,
                                               unsigned* __restrict__ hist2) {
    int i = blockIdx.x * blockDim.x + threadIdx.x;
    unsigned key = fkey(alpha[i]);
    if ((key >> 16) == info[0]) atomicAdd(&hist2[key & 0xFFFFu], 1u);
}

__global__ __launch_bounds__(256) void k_select(const float* __restrict__ alpha,
                                                const unsigned* __restrict__ info,
                                                unsigned* __restrict__ cnt,
                                                float* __restrict__ vals,
                                                int* __restrict__ idx) {
    int i = blockIdx.x * blockDim.x + threadIdx.x;
    float a = alpha[i];
    unsigned key = fkey(a);
    unsigned thr = info[2];
    if (key > thr) {
        unsigned p = atomicAdd(&cnt[0], 1u);
        vals[p] = a; idx[p] = i;
    } else if (key == thr) {
        unsigned t = atomicAdd(&cnt[1], 1u);
        if (t < info[4]) {
            unsigned p = info[3] + t;
            vals[p] = a; idx[p] = i;
        }
    }
}

// Fused softmax + attention gather. 128 blocks x 512 threads; each block
// redundantly computes softmax stats over the 1024 vals (L2-resident), then
// gathers its 8 rows into part[j] (deterministic fixed order).
__global__ __launch_bounds__(512) void k_attn(const float* __restrict__ hs,
                                              const float* __restrict__ vals,
                                              const int* __restrict__ idx,
                                              float* __restrict__ part) {
    __shared__ float red[512];
    int t = threadIdx.x, j = blockIdx.x;
    float v0 = vals[t], v1 = vals[t + 512];
    red[t] = fmaxf(v0, v1);
    __syncthreads();
    for (int s = 256; s > 0; s >>= 1) { if (t < s) red[t] = fmaxf(red[t], red[t + s]); __syncthreads(); }
    float m = red[0];
    __syncthreads();
    red[t] = expf(v0 - m) + expf(v1 - m);
    __syncthreads();
    for (int s = 256; s > 0; s >>= 1) { if (t < s) red[t] += red[t + s]; __syncthreads(); }
    float S = red[0];
    float acc = 0.f;
    #pragma unroll
    for (int k = j * 8; k < j * 8 + 8; ++k) {
        float w = expf(vals[k] - m) / S;
        acc = fmaf(w, hs[(size_t)idx[k] * E_ + t], acc);
    }
    part[(size_t)j * E_ + t] = acc;
}

// One wave per gate-row: gi = w_ih@x + b_ih, gh = w_hh@h + b_hh.
__global__ __launch_bounds__(256) void k_gru(const float* __restrict__ wih,
                                             const float* __restrict__ whh,
                                             const float* __restrict__ bih,
                                             const float* __restrict__ bhh,
                                             const float* __restrict__ ws_v,
                                             const float* __restrict__ score_s,
                                             const float* __restrict__ h_in,
                                             float* __restrict__ gi,
                                             float* __restrict__ gh) {
    __shared__ float x[1025 + 512];
    int t = threadIdx.x;
    float ss = score_s[0];
    float pos = ss >= 0.5f ? 1.f : 0.f;
    for (int c = t; c < 1025; c += 256) {
        float xv;
        if (c < 512)       xv = ws_v[c] * pos;
        else if (c < 1024) xv = ws_v[c - 512] * (1.f - pos);
        else               xv = ss;
        x[c] = xv;
    }
    for (int c = t; c < 512; c += 256) x[1025 + c] = h_in[c];
    __syncthreads();
    int wave = t >> 6, lane = t & 63;
    int row = blockIdx.x * 4 + wave;
    const float* wr = wih + (size_t)row * 1025;
    float s1 = 0.f;
    for (int c = lane; c < 1025; c += 64) s1 = fmaf(wr[c], x[c], s1);
    const float* hr = whh + (size_t)row * 512;
    float s2 = 0.f;
    #pragma unroll
    for (int c = lane; c < 512; c += 64) s2 = fmaf(hr[c], x[1025 + c], s2);
    #pragma unroll
    for (int m = 32; m; m >>= 1) {
        s1 += __shfl_xor(s1, m, 64);
        s2 += __shfl_xor(s2, m, 64);
    }
    if (lane == 0) { gi[row] = s1 + bih[row]; gh[row] = s2 + bhh[row]; }
}

// Fused GRU-finalize + score (one 512-thread block).
__global__ __launch_bounds__(512) void k_final(const float* __restrict__ gi,
                                               const float* __restrict__ gh,
                                               const float* __restrict__ h_in,
                                               const float* __restrict__ part,
                                               const float* __restrict__ ws_v,
                                               const float* __restrict__ w_score,
                                               const float* __restrict__ b_score,
                                               float* __restrict__ out) {
    __shared__ float red[512];
    int j = threadIdx.x;
    // GRU finalize
    float r = 1.f / (1.f + expf(-(gi[j] + gh[j])));
    float z = 1.f / (1.f + expf(-(gi[H_ + j] + gh[H_ + j])));
    float n = tanhf(gi[2 * H_ + j] + r * gh[2 * H_ + j]);
    float hp = h_in[j];
    float hn = (1.f - z) * n + z * hp;
    out[1 + j] = hn;                          // h_new
    out[OUT_HS + (size_t)T_ * E_ + j] = hn;   // hs_new last row
    // Score: reduce 128 attn partials, dot with w_score
    float attn = 0.f;
    for (int jj = 0; jj < 128; ++jj) attn += part[(size_t)jj * E_ + j];
    float d = ws_v[j] * w_score[j] + attn * w_score[512 + j] + hp * w_score[1024 + j];
    if (j == 0) d += 1024.0f * w_score[1536] + b_score[0];
    red[j] = d;
    __syncthreads();
    for (int s = 256; s > 0; s >>= 1) { if (j < s) red[j] += red[j + s]; __syncthreads(); }
    if (j == 0) out[0] = red[0];
}

extern "C" void kernel_launch(void* const* d_in, const int* in_sizes, int n_in,
                              void* d_out, int out_size, void* d_ws, size_t ws_size,
                              hipStream_t stream) {
    const int*   topic   = (const int*)d_in[0];
    const float* score_s = (const float*)d_in[1];
    const float* emb     = (const float*)d_in[2];
    const float* h_in    = (const float*)d_in[3];
    const float* vs      = (const float*)d_in[4];
    const float* hs      = (const float*)d_in[5];
    const float* w_ih    = (const float*)d_in[6];
    const float* w_hh    = (const float*)d_in[7];
    const float* b_ih    = (const float*)d_in[8];
    const float* b_hh    = (const float*)d_in[9];
    const float* w_score = (const float*)d_in[10];
    const float* b_score = (const float*)d_in[11];
    float* out = (float*)d_out;

    float*    wsf   = (float*)d_ws;
    float*    v_ws  = wsf + OFF_V;
    float*    alpha = wsf + OFF_ALPHA;
    unsigned* hist1 = (unsigned*)(wsf + OFF_HIST1);
    unsigned* hist2 = (unsigned*)(wsf + OFF_HIST2);
    unsigned* cnt   = (unsigned*)(wsf + OFF_CNT);
    unsigned* info  = (unsigned*)(wsf + OFF_INFO);
    float*    vals  = wsf + OFF_VALS;
    int*      idx   = (int*)(wsf + OFF_IDX);
    float*    part  = wsf + OFF_ALPHA;  // alpha dead after k_select; reuse as partials
    float*    gi    = wsf + OFF_GI;
    float*    gh    = wsf + OFF_GH;

    // 1) v + zero-init (blocks 0..128 zero ZERO_N u32; block 129 computes v)
    hipLaunchKernelGGL(k_init, dim3(130), dim3(1024), 0, stream,
                       topic, emb, v_ws, hist1, out);
    // 2) fused copies + alpha + hist1 (2 rows/wave)
    hipLaunchKernelGGL(k_mega, dim3(2 * (T_ / 8)), dim3(256), 0, stream,
                       vs, hs, v_ws, alpha, hist1, out);
    // 3-6) exact radix-select of top-K (fully parallel scans)
    hipLaunchKernelGGL(k_scan, dim3(1), dim3(256), 0, stream, hist1, info, 0);
    hipLaunchKernelGGL(k_hist2, dim3(T_ / 256), dim3(256), 0, stream, alpha, info, hist2);
    hipLaunchKernelGGL(k_scan, dim3(1), dim3(256), 0, stream, hist2, info, 1);
    hipLaunchKernelGGL(k_select, dim3(T_ / 256), dim3(256), 0, stream, alpha, info, cnt, vals, idx);
    // 7) fused softmax + attention gather (partials into dead alpha region)
    hipLaunchKernelGGL(k_attn, dim3(128), dim3(512), 0, stream, hs, vals, idx, part);
    // 8) GRU gates
    hipLaunchKernelGGL(k_gru, dim3(384), dim3(256), 0, stream,
                       w_ih, w_hh, b_ih, b_hh, v_ws, score_s, h_in, gi, gh);
    // 9) fused GRU-finalize + score
    hipLaunchKernelGGL(k_final, dim3(1), dim3(512), 0, stream,
                       gi, gh, h_in, part, v_ws, w_score, b_score, out);
}

// Round 8
// 235.754 us; speedup vs baseline: 1.9573x; 1.0642x over previous
//
#include <hip/hip_runtime.h>
#include <math.h>

// Problem constants (from reference)
constexpr int T_ = 131072;
constexpr int E_ = 512;
constexpr int H_ = 512;
constexpr int K_ = 1024;
constexpr int L_ = 128;

typedef __attribute__((ext_vector_type(4))) float f32x4;

// Workspace layout (element offsets; floats unless noted)
constexpr size_t OFF_V     = 0;                    // 512 f
constexpr size_t OFF_ALPHA = 512;                  // 131072 f (reused as attn partials)
constexpr size_t OFF_HIST1 = OFF_ALPHA + T_;       // 65536 u32
constexpr size_t OFF_HIST2 = OFF_HIST1 + 65536;    // 65536 u32
constexpr size_t OFF_CNT   = OFF_HIST2 + 65536;    // 2 u32
constexpr size_t OFF_INFO  = OFF_CNT + 2;          // 8 u32
constexpr size_t OFF_VALS  = OFF_INFO + 8;         // 1024 f
constexpr size_t OFF_IDX   = OFF_VALS + K_;        // 1024 i32
constexpr size_t OFF_GI    = OFF_IDX + K_;         // 1536 f
constexpr size_t OFF_GH    = OFF_GI + 3 * H_;      // 1536 f

// Zeroed-per-call contiguous region: hist1 + hist2 + cnt
constexpr int ZERO_N = 65536 + 65536 + 2;

// Output layout: score(1) | h_new(512) | vs_new((T+1)*512) | hs_new((T+1)*512)
constexpr size_t OUT_VS = 513;
constexpr size_t OUT_HS = 513 + (size_t)(T_ + 1) * E_;

// Mega grid: 384 GRU blocks + 32768 vs blocks + 32768 hs blocks
constexpr int NB_GRU = 384;

// JOURNAL (measured):
//  R4: low-cardinality chunk atomic in mega -> 40K-deep serialization, 860us. NEVER.
//  R5: separate-kernel tail + parallel LDS scans = 244.9us (known good baseline).
//  R6: software spin grid-barrier tail fusion (5 barriers, 512 blocks, cross-XCD
//      polling) = 461us. Kernel-boundary sync (~2-4us) is CHEAPER than device-scope
//      spin barriers (~30-40us each) on 8-XCD MI355X. NEVER again.
//  R7: mega 2 rows/wave = 250.9us, neutral-negative. Mega not issue-depth-limited.
//  R4 profile: mega FETCH=262MB for 512MB input -> L3 retains ~half across replays;
//      mega HBM ~840MB/dispatch.
//  This round: R5 exact + GRU gates folded into mega as 384 leading blocks (sole change).

__device__ __forceinline__ unsigned fkey(float f) {
    unsigned u = __float_as_uint(f);
    return (u & 0x80000000u) ? ~u : (u | 0x80000000u);  // ascending key == ascending float
}

// Last block: v = mean(emb[topic]) (two 512-thread halves, deterministic order).
// Other blocks: zero hist1+hist2+cnt (ZERO_N u32, contiguous).
__global__ __launch_bounds__(1024) void k_init(const int* __restrict__ topic,
                                               const float* __restrict__ emb,
                                               float* __restrict__ ws_v,
                                               unsigned* __restrict__ zero_base,
                                               float* __restrict__ out) {
    if (blockIdx.x == gridDim.x - 1) {
        __shared__ float part[512];
        int t = threadIdx.x;
        int e = t & 511, g = t >> 9;       // g in {0,1}
        float s = 0.f;
        #pragma unroll 8
        for (int l = g * 64; l < g * 64 + 64; ++l) {
            int tp = topic[l];
            s += emb[(size_t)tp * E_ + e];
        }
        if (g == 1) part[e] = s;
        __syncthreads();
        if (g == 0) {
            float v = (s + part[e]) * (1.0f / L_);
            ws_v[e] = v;
            out[OUT_VS + (size_t)T_ * E_ + e] = v;  // vs_new last row
        }
    } else {
        int i = blockIdx.x * blockDim.x + threadIdx.x;
        if (i < ZERO_N) zero_base[i] = 0u;
    }
}

// Mega kernel: {GRU gates (blocks 0..383)} + {vs copy + alpha dot + hist1} +
// {hs copy}. GRU is independent of the copy stream (needs only v from k_init
// and inputs) -> rides the mega dispatch instead of a serial tail launch.
// Copy: NT float4 loads+stores (R5-verified), shuffle-rotate realignment for
// the 4B-misaligned output rows. ONE atomic per row to the 65536-bin hist
// (~2/bin; NEVER a low-cardinality counter here - see R4).
__global__ __launch_bounds__(256) void k_mega(const float* __restrict__ vs,
                                              const float* __restrict__ hs,
                                              const float* __restrict__ ws_v,
                                              float* __restrict__ alpha,
                                              unsigned* __restrict__ hist1,
                                              const float* __restrict__ wih,
                                              const float* __restrict__ whh,
                                              const float* __restrict__ bih,
                                              const float* __restrict__ bhh,
                                              const float* __restrict__ score_s,
                                              const float* __restrict__ h_in,
                                              float* __restrict__ gi,
                                              float* __restrict__ gh,
                                              float* __restrict__ out) {
    __shared__ float x[1025 + 512];
    int t = threadIdx.x;
    int wave = t >> 6, lane = t & 63;
    int b = blockIdx.x;
    if (b < NB_GRU) {
        // ---- GRU gates: one gate-row per wave ----
        float ss = score_s[0];
        float pos = ss >= 0.5f ? 1.f : 0.f;
        for (int c = t; c < 1025; c += 256) {
            float xv;
            if (c < 512)       xv = ws_v[c] * pos;
            else if (c < 1024) xv = ws_v[c - 512] * (1.f - pos);
            else               xv = ss;
            x[c] = xv;
        }
        for (int c = t; c < 512; c += 256) x[1025 + c] = h_in[c];
        __syncthreads();
        int row = b * 4 + wave;
        const float* wr = wih + (size_t)row * 1025;
        float s1 = 0.f;
        for (int c = lane; c < 1025; c += 64) s1 = fmaf(wr[c], x[c], s1);
        const float* hr = whh + (size_t)row * 512;
        float s2 = 0.f;
        #pragma unroll
        for (int c = lane; c < 512; c += 64) s2 = fmaf(hr[c], x[1025 + c], s2);
        #pragma unroll
        for (int m = 32; m; m >>= 1) {
            s1 += __shfl_xor(s1, m, 64);
            s2 += __shfl_xor(s2, m, 64);
        }
        if (lane == 0) { gi[row] = s1 + bih[row]; gh[row] = s2 + bhh[row]; }
        return;
    }
    // ---- Copy + alpha halves ----
    b -= NB_GRU;
    bool is_vs = b < (T_ / 4);
    int row = (is_vs ? b : b - T_ / 4) * 4 + wave;
    const f32x4* src4 = (const f32x4*)((is_vs ? vs : hs) + (size_t)row * E_);
    f32x4 a0 = __builtin_nontemporal_load(&src4[lane]);
    f32x4 a1 = __builtin_nontemporal_load(&src4[lane + 64]);
    if (is_vs) {
        const f32x4* v4 = (const f32x4*)ws_v;
        f32x4 b0 = v4[lane];
        f32x4 b1 = v4[lane + 64];
        float dot = 0.f;
        dot = fmaf(a0.x, b0.x, dot); dot = fmaf(a0.y, b0.y, dot);
        dot = fmaf(a0.z, b0.z, dot); dot = fmaf(a0.w, b0.w, dot);
        dot = fmaf(a1.x, b1.x, dot); dot = fmaf(a1.y, b1.y, dot);
        dot = fmaf(a1.z, b1.z, dot); dot = fmaf(a1.w, b1.w, dot);
        #pragma unroll
        for (int m = 32; m; m >>= 1) dot += __shfl_xor(dot, m, 64);
        if (lane == 0) {
            alpha[row] = dot;
            atomicAdd(&hist1[fkey(dot) >> 16], 1u);
        }
    }
    // Shuffle-rotate realignment
    int nl = (lane + 1) & 63;
    float n0x = __shfl(a0.x, nl, 64), n0y = __shfl(a0.y, nl, 64), n0z = __shfl(a0.z, nl, 64);
    float n1x = __shfl(a1.x, nl, 64), n1y = __shfl(a1.y, nl, 64), n1z = __shfl(a1.z, nl, 64);
    float* dst = out + (is_vs ? OUT_VS : OUT_HS) + (size_t)row * E_;
    f32x4* d4 = (f32x4*)(dst + 3);            // 16B-aligned
    bool last = (lane == 63);
    f32x4 lo;
    lo.x = a0.w;
    lo.y = last ? n1x : n0x;   // lane 63: e[256..258] = a1.xyz of lane 0
    lo.z = last ? n1y : n0y;
    lo.w = last ? n1z : n0z;
    __builtin_nontemporal_store(lo, &d4[lane]);
    if (!last) {
        f32x4 hi;
        hi.x = a1.w; hi.y = n1x; hi.z = n1y; hi.w = n1z;
        __builtin_nontemporal_store(hi, &d4[lane + 64]);
    }
    if (lane == 0) { dst[0] = a0.x; dst[1] = a0.y; dst[2] = a0.z; }
    if (last) dst[511] = a1.w;
}

// Fully-parallel descending select over a 65536-bin histogram (verified R5).
__global__ __launch_bounds__(256) void k_scan(const unsigned* __restrict__ hist,
                                              unsigned* __restrict__ info, int pass) {
    __shared__ unsigned ps[256];
    __shared__ unsigned s_chunk, s_above;
    int t = threadIdx.x;
    unsigned Kwant = (pass == 0) ? (unsigned)K_ : ((unsigned)K_ - info[1]);
    // phase 1: chunk t covers bins [65536-256(t+1), 65536-256t)
    unsigned base = 65536u - (unsigned)(t + 1) * 256u;
    unsigned s = 0;
    for (int j = 0; j < 256; ++j) s += hist[base + j];
    ps[t] = s;
    __syncthreads();
    // phase 2: inclusive scan (descending-chunk prefix)
    #pragma unroll
    for (int off = 1; off < 256; off <<= 1) {
        unsigned v = (t >= off) ? ps[t - off] : 0u;
        __syncthreads();
        ps[t] += v;
        __syncthreads();
    }
    unsigned incl = ps[t], excl = incl - s;
    if (excl < Kwant && incl >= Kwant) { s_chunk = (unsigned)t; s_above = excl; }
    __syncthreads();
    unsigned c = s_chunk;
    unsigned Kw2 = Kwant - s_above;
    // phase 3: scan winner chunk's bins, descending: bin = 65535-256c-t
    unsigned bin = 65535u - c * 256u - (unsigned)t;
    unsigned b = hist[bin];
    __syncthreads();
    ps[t] = b;
    __syncthreads();
    #pragma unroll
    for (int off = 1; off < 256; off <<= 1) {
        unsigned v = (t >= off) ? ps[t - off] : 0u;
        __syncthreads();
        ps[t] += v;
        __syncthreads();
    }
    unsigned inc2 = ps[t], ex2 = inc2 - b;
    if (ex2 < Kw2 && inc2 >= Kw2) {
        unsigned cnt_above = s_above + ex2;
        if (pass == 0) { info[0] = bin; info[1] = cnt_above; }
        else {
            info[2] = (info[0] << 16) | bin;
            info[3] = info[1] + cnt_above;
            info[4] = (unsigned)K_ - info[3];
        }
    }
}

__global__ __launch_bounds__(256) void k_hist2(const float* __restrict__ alpha,
                                               const unsigned* __restrict__ info,
                                               unsigned* __restrict__ hist2) {
    int i = blockIdx.x * blockDim.x + threadIdx.x;
    unsigned key = fkey(alpha[i]);
    if ((key >> 16) == info[0]) atomicAdd(&hist2[key & 0xFFFFu], 1u);
}

__global__ __launch_bounds__(256) void k_select(const float* __restrict__ alpha,
                                                const unsigned* __restrict__ info,
                                                unsigned* __restrict__ cnt,
                                                float* __restrict__ vals,
                                                int* __restrict__ idx) {
    int i = blockIdx.x * blockDim.x + threadIdx.x;
    float a = alpha[i];
    unsigned key = fkey(a);
    unsigned thr = info[2];
    if (key > thr) {
        unsigned p = atomicAdd(&cnt[0], 1u);
        vals[p] = a; idx[p] = i;
    } else if (key == thr) {
        unsigned t = atomicAdd(&cnt[1], 1u);
        if (t < info[4]) {
            unsigned p = info[3] + t;
            vals[p] = a; idx[p] = i;
        }
    }
}

// Fused softmax + attention gather. 128 blocks x 512 threads; each block
// redundantly computes softmax stats over the 1024 vals (L2-resident), then
// gathers its 8 rows into part[j] (deterministic fixed order).
__global__ __launch_bounds__(512) void k_attn(const float* __restrict__ hs,
                                              const float* __restrict__ vals,
                                              const int* __restrict__ idx,
                                              float* __restrict__ part) {
    __shared__ float red[512];
    int t = threadIdx.x, j = blockIdx.x;
    float v0 = vals[t], v1 = vals[t + 512];
    red[t] = fmaxf(v0, v1);
    __syncthreads();
    for (int s = 256; s > 0; s >>= 1) { if (t < s) red[t] = fmaxf(red[t], red[t + s]); __syncthreads(); }
    float m = red[0];
    __syncthreads();
    red[t] = expf(v0 - m) + expf(v1 - m);
    __syncthreads();
    for (int s = 256; s > 0; s >>= 1) { if (t < s) red[t] += red[t + s]; __syncthreads(); }
    float S = red[0];
    float acc = 0.f;
    #pragma unroll
    for (int k = j * 8; k < j * 8 + 8; ++k) {
        float w = expf(vals[k] - m) / S;
        acc = fmaf(w, hs[(size_t)idx[k] * E_ + t], acc);
    }
    part[(size_t)j * E_ + t] = acc;
}

// Fused GRU-finalize + score (one 512-thread block).
__global__ __launch_bounds__(512) void k_final(const float* __restrict__ gi,
                                               const float* __restrict__ gh,
                                               const float* __restrict__ h_in,
                                               const float* __restrict__ part,
                                               const float* __restrict__ ws_v,
                                               const float* __restrict__ w_score,
                                               const float* __restrict__ b_score,
                                               float* __restrict__ out) {
    __shared__ float red[512];
    int j = threadIdx.x;
    // GRU finalize
    float r = 1.f / (1.f + expf(-(gi[j] + gh[j])));
    float z = 1.f / (1.f + expf(-(gi[H_ + j] + gh[H_ + j])));
    float n = tanhf(gi[2 * H_ + j] + r * gh[2 * H_ + j]);
    float hp = h_in[j];
    float hn = (1.f - z) * n + z * hp;
    out[1 + j] = hn;                          // h_new
    out[OUT_HS + (size_t)T_ * E_ + j] = hn;   // hs_new last row
    // Score: reduce 128 attn partials, dot with w_score
    float attn = 0.f;
    for (int jj = 0; jj < 128; ++jj) attn += part[(size_t)jj * E_ + j];
    float d = ws_v[j] * w_score[j] + attn * w_score[512 + j] + hp * w_score[1024 + j];
    if (j == 0) d += 1024.0f * w_score[1536] + b_score[0];
    red[j] = d;
    __syncthreads();
    for (int s = 256; s > 0; s >>= 1) { if (j < s) red[j] += red[j + s]; __syncthreads(); }
    if (j == 0) out[0] = red[0];
}

extern "C" void kernel_launch(void* const* d_in, const int* in_sizes, int n_in,
                              void* d_out, int out_size, void* d_ws, size_t ws_size,
                              hipStream_t stream) {
    const int*   topic   = (const int*)d_in[0];
    const float* score_s = (const float*)d_in[1];
    const float* emb     = (const float*)d_in[2];
    const float* h_in    = (const float*)d_in[3];
    const float* vs      = (const float*)d_in[4];
    const float* hs      = (const float*)d_in[5];
    const float* w_ih    = (const float*)d_in[6];
    const float* w_hh    = (const float*)d_in[7];
    const float* b_ih    = (const float*)d_in[8];
    const float* b_hh    = (const float*)d_in[9];
    const float* w_score = (const float*)d_in[10];
    const float* b_score = (const float*)d_in[11];
    float* out = (float*)d_out;

    float*    wsf   = (float*)d_ws;
    float*    v_ws  = wsf + OFF_V;
    float*    alpha = wsf + OFF_ALPHA;
    unsigned* hist1 = (unsigned*)(wsf + OFF_HIST1);
    unsigned* hist2 = (unsigned*)(wsf + OFF_HIST2);
    unsigned* cnt   = (unsigned*)(wsf + OFF_CNT);
    unsigned* info  = (unsigned*)(wsf + OFF_INFO);
    float*    vals  = wsf + OFF_VALS;
    int*      idx   = (int*)(wsf + OFF_IDX);
    float*    part  = wsf + OFF_ALPHA;  // alpha dead after k_select; reuse as partials
    float*    gi    = wsf + OFF_GI;
    float*    gh    = wsf + OFF_GH;

    // 1) v + zero-init (blocks 0..128 zero ZERO_N u32; block 129 computes v)
    hipLaunchKernelGGL(k_init, dim3(130), dim3(1024), 0, stream,
                       topic, emb, v_ws, hist1, out);
    // 2) fused GRU gates + copies + alpha + hist1
    hipLaunchKernelGGL(k_mega, dim3(NB_GRU + 2 * (T_ / 4)), dim3(256), 0, stream,
                       vs, hs, v_ws, alpha, hist1,
                       w_ih, w_hh, b_ih, b_hh, score_s, h_in, gi, gh, out);
    // 3-6) exact radix-select of top-K (fully parallel scans)
    hipLaunchKernelGGL(k_scan, dim3(1), dim3(256), 0, stream, hist1, info, 0);
    hipLaunchKernelGGL(k_hist2, dim3(T_ / 256), dim3(256), 0, stream, alpha, info, hist2);
    hipLaunchKernelGGL(k_scan, dim3(1), dim3(256), 0, stream, hist2, info, 1);
    hipLaunchKernelGGL(k_select, dim3(T_ / 256), dim3(256), 0, stream, alpha, info, cnt, vals, idx);
    // 7) fused softmax + attention gather (partials into dead alpha region)
    hipLaunchKernelGGL(k_attn, dim3(128), dim3(512), 0, stream, hs, vals, idx, part);
    // 8) fused GRU-finalize + score
    hipLaunchKernelGGL(k_final, dim3(1), dim3(512), 0, stream,
                       gi, gh, h_in, part, v_ws, w_score, b_score, out);
}

// Round 9
// 227.563 us; speedup vs baseline: 2.0277x; 1.0360x over previous
//
#include <hip/hip_runtime.h>
#include <math.h>

// Problem constants (from reference)
constexpr int T_ = 131072;
constexpr int E_ = 512;
constexpr int H_ = 512;
constexpr int K_ = 1024;
constexpr int L_ = 128;
constexpr int CAND_CAP = 16384;

typedef __attribute__((ext_vector_type(4))) float f32x4;

// Workspace layout (element offsets; floats unless noted)
constexpr size_t OFF_V     = 0;                    // 512 f
constexpr size_t OFF_ALPHA = 512;                  // 131072 f (reused as attn partials)
constexpr size_t OFF_HIST1 = OFF_ALPHA + T_;       // 65536 u32
constexpr size_t OFF_CNT   = OFF_HIST1 + 65536;    // 2 u32 (def count, cand count)
constexpr size_t OFF_INFO  = OFF_CNT + 2;          // 8 u32
constexpr size_t OFF_VALS  = OFF_INFO + 8;         // 1024 f
constexpr size_t OFF_IDX   = OFF_VALS + K_;        // 1024 i32
constexpr size_t OFF_CANDV = OFF_IDX + K_;         // 16384 f
constexpr size_t OFF_CANDI = OFF_CANDV + CAND_CAP; // 16384 i32
constexpr size_t OFF_GI    = OFF_CANDI + CAND_CAP; // 1536 f
constexpr size_t OFF_GH    = OFF_GI + 3 * H_;      // 1536 f

// Zeroed-per-call contiguous region: hist1 + cnt
constexpr int ZERO_N = 65536 + 2;

// Output layout: score(1) | h_new(512) | vs_new((T+1)*512) | hs_new((T+1)*512)
constexpr size_t OUT_VS = 513;
constexpr size_t OUT_HS = 513 + (size_t)(T_ + 1) * E_;

// Mega grid: 384 GRU blocks + 32768 vs blocks + 32768 hs blocks
constexpr int NB_GRU = 384;

// JOURNAL (measured):
//  R4: low-cardinality chunk atomic in mega -> 40K-deep serialization, 860us. NEVER.
//  R5: separate-kernel tail + parallel LDS scans = 244.9us.
//  R6: software spin grid-barriers (512 blocks, cross-XCD) = +43us/barrier. NEVER.
//  R7: mega 2 rows/wave neutral (not issue-depth-limited).
//  R8: GRU gates folded into mega as leading blocks = 235.75us (-9). Tail launches
//      cost ~2-4us each + latency-bound kernel time.
//  R4 profile: mega FETCH=262MB for 512MB input (L3 retains ~half; NT stores
//      don't pollute L3). Mega ~190us at ~4.3TB/s HBM-equivalent.
//  This round: single radix pass + candidate-rank resolve replaces hist2/scan1/
//      select (8 kernels -> 7, one less full alpha pass).

__device__ __forceinline__ unsigned fkey(float f) {
    unsigned u = __float_as_uint(f);
    return (u & 0x80000000u) ? ~u : (u | 0x80000000u);  // ascending key == ascending float
}

// Last block: v = mean(emb[topic]) (two 512-thread halves, deterministic order).
// Other blocks: zero hist1+cnt (ZERO_N u32, contiguous).
__global__ __launch_bounds__(1024) void k_init(const int* __restrict__ topic,
                                               const float* __restrict__ emb,
                                               float* __restrict__ ws_v,
                                               unsigned* __restrict__ zero_base,
                                               float* __restrict__ out) {
    if (blockIdx.x == gridDim.x - 1) {
        __shared__ float part[512];
        int t = threadIdx.x;
        int e = t & 511, g = t >> 9;       // g in {0,1}
        float s = 0.f;
        #pragma unroll 8
        for (int l = g * 64; l < g * 64 + 64; ++l) {
            int tp = topic[l];
            s += emb[(size_t)tp * E_ + e];
        }
        if (g == 1) part[e] = s;
        __syncthreads();
        if (g == 0) {
            float v = (s + part[e]) * (1.0f / L_);
            ws_v[e] = v;
            out[OUT_VS + (size_t)T_ * E_ + e] = v;  // vs_new last row
        }
    } else {
        int i = blockIdx.x * blockDim.x + threadIdx.x;
        if (i < ZERO_N) zero_base[i] = 0u;
    }
}

// Mega kernel (R8-verified): {GRU gates (blocks 0..383)} + {vs copy + alpha dot
// + hist1} + {hs copy}. NT float4 loads+stores, shuffle-rotate realignment.
// ONE atomic per row to the 65536-bin hist (~2/bin; NEVER low-cardinality - R4).
__global__ __launch_bounds__(256) void k_mega(const float* __restrict__ vs,
                                              const float* __restrict__ hs,
                                              const float* __restrict__ ws_v,
                                              float* __restrict__ alpha,
                                              unsigned* __restrict__ hist1,
                                              const float* __restrict__ wih,
                                              const float* __restrict__ whh,
                                              const float* __restrict__ bih,
                                              const float* __restrict__ bhh,
                                              const float* __restrict__ score_s,
                                              const float* __restrict__ h_in,
                                              float* __restrict__ gi,
                                              float* __restrict__ gh,
                                              float* __restrict__ out) {
    __shared__ float x[1025 + 512];
    int t = threadIdx.x;
    int wave = t >> 6, lane = t & 63;
    int b = blockIdx.x;
    if (b < NB_GRU) {
        // ---- GRU gates: one gate-row per wave ----
        float ss = score_s[0];
        float pos = ss >= 0.5f ? 1.f : 0.f;
        for (int c = t; c < 1025; c += 256) {
            float xv;
            if (c < 512)       xv = ws_v[c] * pos;
            else if (c < 1024) xv = ws_v[c - 512] * (1.f - pos);
            else               xv = ss;
            x[c] = xv;
        }
        for (int c = t; c < 512; c += 256) x[1025 + c] = h_in[c];
        __syncthreads();
        int row = b * 4 + wave;
        const float* wr = wih + (size_t)row * 1025;
        float s1 = 0.f;
        for (int c = lane; c < 1025; c += 64) s1 = fmaf(wr[c], x[c], s1);
        const float* hr = whh + (size_t)row * 512;
        float s2 = 0.f;
        #pragma unroll
        for (int c = lane; c < 512; c += 64) s2 = fmaf(hr[c], x[1025 + c], s2);
        #pragma unroll
        for (int m = 32; m; m >>= 1) {
            s1 += __shfl_xor(s1, m, 64);
            s2 += __shfl_xor(s2, m, 64);
        }
        if (lane == 0) { gi[row] = s1 + bih[row]; gh[row] = s2 + bhh[row]; }
        return;
    }
    // ---- Copy + alpha halves ----
    b -= NB_GRU;
    bool is_vs = b < (T_ / 4);
    int row = (is_vs ? b : b - T_ / 4) * 4 + wave;
    const f32x4* src4 = (const f32x4*)((is_vs ? vs : hs) + (size_t)row * E_);
    f32x4 a0 = __builtin_nontemporal_load(&src4[lane]);
    f32x4 a1 = __builtin_nontemporal_load(&src4[lane + 64]);
    if (is_vs) {
        const f32x4* v4 = (const f32x4*)ws_v;
        f32x4 b0 = v4[lane];
        f32x4 b1 = v4[lane + 64];
        float dot = 0.f;
        dot = fmaf(a0.x, b0.x, dot); dot = fmaf(a0.y, b0.y, dot);
        dot = fmaf(a0.z, b0.z, dot); dot = fmaf(a0.w, b0.w, dot);
        dot = fmaf(a1.x, b1.x, dot); dot = fmaf(a1.y, b1.y, dot);
        dot = fmaf(a1.z, b1.z, dot); dot = fmaf(a1.w, b1.w, dot);
        #pragma unroll
        for (int m = 32; m; m >>= 1) dot += __shfl_xor(dot, m, 64);
        if (lane == 0) {
            alpha[row] = dot;
            atomicAdd(&hist1[fkey(dot) >> 16], 1u);
        }
    }
    // Shuffle-rotate realignment
    int nl = (lane + 1) & 63;
    float n0x = __shfl(a0.x, nl, 64), n0y = __shfl(a0.y, nl, 64), n0z = __shfl(a0.z, nl, 64);
    float n1x = __shfl(a1.x, nl, 64), n1y = __shfl(a1.y, nl, 64), n1z = __shfl(a1.z, nl, 64);
    float* dst = out + (is_vs ? OUT_VS : OUT_HS) + (size_t)row * E_;
    f32x4* d4 = (f32x4*)(dst + 3);            // 16B-aligned
    bool last = (lane == 63);
    f32x4 lo;
    lo.x = a0.w;
    lo.y = last ? n1x : n0x;   // lane 63: e[256..258] = a1.xyz of lane 0
    lo.z = last ? n1y : n0y;
    lo.w = last ? n1z : n0z;
    __builtin_nontemporal_store(lo, &d4[lane]);
    if (!last) {
        f32x4 hi;
        hi.x = a1.w; hi.y = n1x; hi.z = n1y; hi.w = n1z;
        __builtin_nontemporal_store(hi, &d4[lane + 64]);
    }
    if (lane == 0) { dst[0] = a0.x; dst[1] = a0.y; dst[2] = a0.z; }
    if (last) dst[511] = a1.w;
}

// Parallel descending scan (pass 0 only): find bin1 containing the Kth largest
// and count_above. info[0]=bin1, info[1]=count_above. (R5-verified structure.)
__global__ __launch_bounds__(256) void k_scan(const unsigned* __restrict__ hist,
                                              unsigned* __restrict__ info) {
    __shared__ unsigned ps[256];
    __shared__ unsigned s_chunk, s_above;
    int t = threadIdx.x;
    unsigned Kwant = (unsigned)K_;
    unsigned base = 65536u - (unsigned)(t + 1) * 256u;
    unsigned s = 0;
    for (int j = 0; j < 256; ++j) s += hist[base + j];
    ps[t] = s;
    __syncthreads();
    #pragma unroll
    for (int off = 1; off < 256; off <<= 1) {
        unsigned v = (t >= off) ? ps[t - off] : 0u;
        __syncthreads();
        ps[t] += v;
        __syncthreads();
    }
    unsigned incl = ps[t], excl = incl - s;
    if (excl < Kwant && incl >= Kwant) { s_chunk = (unsigned)t; s_above = excl; }
    __syncthreads();
    unsigned c = s_chunk;
    unsigned Kw2 = Kwant - s_above;
    unsigned bin = 65535u - c * 256u - (unsigned)t;
    unsigned b = hist[bin];
    __syncthreads();
    ps[t] = b;
    __syncthreads();
    #pragma unroll
    for (int off = 1; off < 256; off <<= 1) {
        unsigned v = (t >= off) ? ps[t - off] : 0u;
        __syncthreads();
        ps[t] += v;
        __syncthreads();
    }
    unsigned inc2 = ps[t], ex2 = inc2 - b;
    if (ex2 < Kw2 && inc2 >= Kw2) {
        info[0] = bin;
        info[1] = s_above + ex2;
    }
}

// One pass over alpha: definite top-K (key>>16 > bin1) straight into vals/idx;
// threshold-bin values (key>>16 == bin1) into candidate buffer (expected ~tens).
__global__ __launch_bounds__(256) void k_collect(const float* __restrict__ alpha,
                                                 const unsigned* __restrict__ info,
                                                 unsigned* __restrict__ cnt,
                                                 float* __restrict__ vals,
                                                 int* __restrict__ idx,
                                                 float* __restrict__ candv,
                                                 int* __restrict__ candi) {
    int i = blockIdx.x * blockDim.x + threadIdx.x;
    float a = alpha[i];
    unsigned hb = fkey(a) >> 16;
    unsigned bin1 = info[0];
    if (hb > bin1) {
        unsigned p = atomicAdd(&cnt[0], 1u);
        vals[p] = a; idx[p] = i;
    } else if (hb == bin1) {
        unsigned q = atomicAdd(&cnt[1], 1u);
        if (q < (unsigned)CAND_CAP) { candv[q] = a; candi[q] = i; }
    }
}

// Exact stable-rank selection among candidates: candidate i is placed at
// vals[ndef + greater_i + eqb_i] if that rank < k2. O(nc^2), nc ~ tens.
__global__ __launch_bounds__(256) void k_resolve(const float* __restrict__ candv,
                                                 const int* __restrict__ candi,
                                                 const unsigned* __restrict__ cnt,
                                                 float* __restrict__ vals,
                                                 int* __restrict__ idx) {
    int t = threadIdx.x;
    unsigned nc = cnt[1] < (unsigned)CAND_CAP ? cnt[1] : (unsigned)CAND_CAP;
    unsigned ndef = cnt[0];
    unsigned k2 = (unsigned)K_ - ndef;
    for (unsigned i = t; i < nc; i += 256) {
        unsigned ki = fkey(candv[i]);
        unsigned greater = 0, eqb = 0;
        for (unsigned j = 0; j < nc; ++j) {
            unsigned kj = fkey(candv[j]);
            greater += (kj > ki) ? 1u : 0u;
            eqb += (kj == ki && j < i) ? 1u : 0u;
        }
        unsigned r = greater + eqb;
        if (r < k2) { vals[ndef + r] = candv[i]; idx[ndef + r] = candi[i]; }
    }
}

// Fused softmax + attention gather (R5-verified). 128 blocks x 512 threads.
__global__ __launch_bounds__(512) void k_attn(const float* __restrict__ hs,
                                              const float* __restrict__ vals,
                                              const int* __restrict__ idx,
                                              float* __restrict__ part) {
    __shared__ float red[512];
    int t = threadIdx.x, j = blockIdx.x;
    float v0 = vals[t], v1 = vals[t + 512];
    red[t] = fmaxf(v0, v1);
    __syncthreads();
    for (int s = 256; s > 0; s >>= 1) { if (t < s) red[t] = fmaxf(red[t], red[t + s]); __syncthreads(); }
    float m = red[0];
    __syncthreads();
    red[t] = expf(v0 - m) + expf(v1 - m);
    __syncthreads();
    for (int s = 256; s > 0; s >>= 1) { if (t < s) red[t] += red[t + s]; __syncthreads(); }
    float S = red[0];
    float acc = 0.f;
    #pragma unroll
    for (int k = j * 8; k < j * 8 + 8; ++k) {
        float w = expf(vals[k] - m) / S;
        acc = fmaf(w, hs[(size_t)idx[k] * E_ + t], acc);
    }
    part[(size_t)j * E_ + t] = acc;
}

// Fused GRU-finalize + score (one 512-thread block, R5-verified).
__global__ __launch_bounds__(512) void k_final(const float* __restrict__ gi,
                                               const float* __restrict__ gh,
                                               const float* __restrict__ h_in,
                                               const float* __restrict__ part,
                                               const float* __restrict__ ws_v,
                                               const float* __restrict__ w_score,
                                               const float* __restrict__ b_score,
                                               float* __restrict__ out) {
    __shared__ float red[512];
    int j = threadIdx.x;
    // GRU finalize
    float r = 1.f / (1.f + expf(-(gi[j] + gh[j])));
    float z = 1.f / (1.f + expf(-(gi[H_ + j] + gh[H_ + j])));
    float n = tanhf(gi[2 * H_ + j] + r * gh[2 * H_ + j]);
    float hp = h_in[j];
    float hn = (1.f - z) * n + z * hp;
    out[1 + j] = hn;                          // h_new
    out[OUT_HS + (size_t)T_ * E_ + j] = hn;   // hs_new last row
    // Score: reduce 128 attn partials, dot with w_score
    float attn = 0.f;
    for (int jj = 0; jj < 128; ++jj) attn += part[(size_t)jj * E_ + j];
    float d = ws_v[j] * w_score[j] + attn * w_score[512 + j] + hp * w_score[1024 + j];
    if (j == 0) d += 1024.0f * w_score[1536] + b_score[0];
    red[j] = d;
    __syncthreads();
    for (int s = 256; s > 0; s >>= 1) { if (j < s) red[j] += red[j + s]; __syncthreads(); }
    if (j == 0) out[0] = red[0];
}

extern "C" void kernel_launch(void* const* d_in, const int* in_sizes, int n_in,
                              void* d_out, int out_size, void* d_ws, size_t ws_size,
                              hipStream_t stream) {
    const int*   topic   = (const int*)d_in[0];
    const float* score_s = (const float*)d_in[1];
    const float* emb     = (const float*)d_in[2];
    const float* h_in    = (const float*)d_in[3];
    const float* vs      = (const float*)d_in[4];
    const float* hs      = (const float*)d_in[5];
    const float* w_ih    = (const float*)d_in[6];
    const float* w_hh    = (const float*)d_in[7];
    const float* b_ih    = (const float*)d_in[8];
    const float* b_hh    = (const float*)d_in[9];
    const float* w_score = (const float*)d_in[10];
    const float* b_score = (const float*)d_in[11];
    float* out = (float*)d_out;

    float*    wsf   = (float*)d_ws;
    float*    v_ws  = wsf + OFF_V;
    float*    alpha = wsf + OFF_ALPHA;
    unsigned* hist1 = (unsigned*)(wsf + OFF_HIST1);
    unsigned* cnt   = (unsigned*)(wsf + OFF_CNT);
    unsigned* info  = (unsigned*)(wsf + OFF_INFO);
    float*    vals  = wsf + OFF_VALS;
    int*      idx   = (int*)(wsf + OFF_IDX);
    float*    candv = wsf + OFF_CANDV;
    int*      candi = (int*)(wsf + OFF_CANDI);
    float*    part  = wsf + OFF_ALPHA;  // alpha dead after k_collect; reuse as partials
    float*    gi    = wsf + OFF_GI;
    float*    gh    = wsf + OFF_GH;

    // 1) v + zero-init (blocks 0..64 zero ZERO_N u32; block 65 computes v)
    hipLaunchKernelGGL(k_init, dim3(66), dim3(1024), 0, stream,
                       topic, emb, v_ws, hist1, out);
    // 2) fused GRU gates + copies + alpha + hist1
    hipLaunchKernelGGL(k_mega, dim3(NB_GRU + 2 * (T_ / 4)), dim3(256), 0, stream,
                       vs, hs, v_ws, alpha, hist1,
                       w_ih, w_hh, b_ih, b_hh, score_s, h_in, gi, gh, out);
    // 3) find threshold bin
    hipLaunchKernelGGL(k_scan, dim3(1), dim3(256), 0, stream, hist1, info);
    // 4) collect definite top-K + threshold-bin candidates
    hipLaunchKernelGGL(k_collect, dim3(T_ / 256), dim3(256), 0, stream,
                       alpha, info, cnt, vals, idx, candv, candi);
    // 5) exact rank-resolve among candidates
    hipLaunchKernelGGL(k_resolve, dim3(1), dim3(256), 0, stream,
                       candv, candi, cnt, vals, idx);
    // 6) fused softmax + attention gather (partials into dead alpha region)
    hipLaunchKernelGGL(k_attn, dim3(128), dim3(512), 0, stream, hs, vals, idx, part);
    // 7) fused GRU-finalize + score
    hipLaunchKernelGGL(k_final, dim3(1), dim3(512), 0, stream,
                       gi, gh, h_in, part, v_ws, w_score, b_score, out);
}